// Round 2
// baseline (349.759 us; speedup 1.0000x reference)
//
#include <hip/hip_runtime.h>

// Problem constants (match reference)
#define BATCH   4096
#define DIM     64
#define NTOT    (BATCH * DIM * DIM)   // 16,777,216 fp32 per tensor
#define NVEC    (NTOT / 4)            // 4,194,304 float4s
#define MRANK   32
#define GAMMA_C   0.1f
#define LAMBDA2_C 0.1f

#define THREADS 256
#define BLOCKS  4096
#define STRIDE  (BLOCKS * THREADS)    // 1,048,576
#define ITERS   (NVEC / STRIDE)       // 4 — exact fit, no bounds checks

// ---------------------------------------------------------------------------
// Single fused kernel.
// Phase 1 (all blocks): sum of (pred-true)^2, exact-fit unrolled float4 loads
//   (8 outstanding dwordx4 per thread), wave+LDS reduce, one atomicAdd/block.
// Phase 2 (last block via atomic ticket): 32 traces computed by 256 threads
//   (8 diag elements each), pairwise rank loss on wave 0, write outputs.
// ws[0] = float accumulator, ws[1] = uint ticket counter (memset to 0).
// ---------------------------------------------------------------------------
__global__ void __launch_bounds__(THREADS)
fused_loss_kernel(const float4* __restrict__ p4, const float4* __restrict__ t4,
                  const float* __restrict__ p, const float* __restrict__ t,
                  float* __restrict__ ws, float* __restrict__ out) {
    const int tid = blockIdx.x * THREADS + threadIdx.x;

    // ---- Phase 1: sum of squares ----
    float4 a[ITERS], b[ITERS];
    #pragma unroll
    for (int k = 0; k < ITERS; ++k) {
        a[k] = p4[tid + k * STRIDE];
        b[k] = t4[tid + k * STRIDE];
    }
    float acc = 0.0f;
    #pragma unroll
    for (int k = 0; k < ITERS; ++k) {
        float dx = a[k].x - b[k].x;
        float dy = a[k].y - b[k].y;
        float dz = a[k].z - b[k].z;
        float dw = a[k].w - b[k].w;
        acc += dx * dx + dy * dy + dz * dz + dw * dw;
    }
    #pragma unroll
    for (int off = 32; off > 0; off >>= 1)
        acc += __shfl_down(acc, off, 64);

    __shared__ float smem[THREADS / 64];
    const int wid  = threadIdx.x >> 6;
    const int lane = threadIdx.x & 63;
    if (lane == 0) smem[wid] = acc;
    __syncthreads();

    __shared__ unsigned s_ticket;
    if (threadIdx.x == 0) {
        float v = smem[0] + smem[1] + smem[2] + smem[3];
        atomicAdd(ws, v);                     // device-scope
        __threadfence();                      // make ws[0] add visible first
        s_ticket = atomicAdd((unsigned*)(ws + 1), 1u);
    }
    __syncthreads();
    if (s_ticket != BLOCKS - 1) return;

    // ---- Phase 2: last block computes traces + rank loss + outputs ----
    __threadfence();  // acquire: see all blocks' ws[0] contributions

    const int tt_ = threadIdx.x;
    const int mat  = tt_ >> 3;   // 0..31
    const int part = tt_ & 7;    // 0..7 → diag elements part*8 .. part*8+7
    float tp = 0.0f, tr = 0.0f;
    #pragma unroll
    for (int i = 0; i < 8; ++i) {
        const int j = part * 8 + i;
        const size_t off = (size_t)mat * (DIM * DIM) + (size_t)j * (DIM + 1);
        tp += p[off];
        tr += t[off];
    }
    __shared__ float redp[THREADS], redt[THREADS];
    redp[tt_] = tp;
    redt[tt_] = tr;
    __syncthreads();

    __shared__ float sp[MRANK], st[MRANK];
    if (tt_ < MRANK) {
        float s1 = 0.0f, s2 = 0.0f;
        #pragma unroll
        for (int i = 0; i < 8; ++i) {
            s1 += redp[tt_ * 8 + i];
            s2 += redt[tt_ * 8 + i];
        }
        sp[tt_] = s1;
        st[tt_] = s2;
    }
    __syncthreads();

    float racc = 0.0f;
    if (tt_ < MRANK) {
        const float pi = sp[tt_];
        const float ti = st[tt_];
        for (int j = tt_ + 1; j < MRANK; ++j) {
            float dt = ti - st[j];
            float dp = pi - sp[j];
            float c = 0.0f;
            if (dt > 0.0f)      c = fmaxf(-dp + GAMMA_C, 0.0f);
            else if (dt < 0.0f) c = fmaxf( dp + GAMMA_C, 0.0f);
            racc += c;
        }
    }
    if (tt_ < 64) {  // whole wave 0 participates in shuffle
        #pragma unroll
        for (int off = 32; off > 0; off >>= 1)
            racc += __shfl_down(racc, off, 64);
        if (tt_ == 0) {
            float total_ss = atomicAdd(ws, 0.0f);  // coherent read
            float eff  = total_ss / (float)NTOT;
            float rank = racc / 496.0f;            // 32*31/2 pairs
            out[0] = eff + LAMBDA2_C * rank;
            out[1] = eff;
            out[2] = rank;
        }
    }
}

extern "C" void kernel_launch(void* const* d_in, const int* in_sizes, int n_in,
                              void* d_out, int out_size, void* d_ws, size_t ws_size,
                              hipStream_t stream) {
    const float* pred = (const float*)d_in[0];
    const float* tru  = (const float*)d_in[1];
    float* out = (float*)d_out;
    float* ws  = (float*)d_ws;

    // ws is poisoned 0xAA before every call — zero accumulator + ticket.
    hipMemsetAsync(ws, 0, 2 * sizeof(float), stream);

    fused_loss_kernel<<<BLOCKS, THREADS, 0, stream>>>(
        (const float4*)pred, (const float4*)tru, pred, tru, ws, out);
}

// Round 3
// 150.964 us; speedup vs baseline: 2.3168x; 2.3168x over previous
//
#include <hip/hip_runtime.h>

// Problem constants (match reference)
#define BATCH   4096
#define DIM     64
#define NTOT    (BATCH * DIM * DIM)   // 16,777,216 fp32 per tensor
#define NVEC    (NTOT / 4)            // 4,194,304 float4s
#define MRANK   32
#define GAMMA_C   0.1f
#define LAMBDA2_C 0.1f

#define THREADS 256
#define BLOCKS  2048
#define STRIDE  (BLOCKS * THREADS)    // 524,288
#define ITERS   (NVEC / STRIDE)       // 8 — exact fit, no bounds checks

// ---------------------------------------------------------------------------
// Kernel 1: per-block partial sum of (pred-true)^2.
// Full preload of 8 float4 pairs (16 global_load_dwordx4 in flight per
// thread). __launch_bounds__(256,2) caps min-occupancy demand so the
// register allocator keeps all loads in flight (~150 VGPRs, no spill).
// NO atomics: partial written with a plain store to partials[blockIdx.x];
// kernel-completion flush + stream order makes it visible to kernel 2.
// ---------------------------------------------------------------------------
__global__ void __launch_bounds__(THREADS, 2)
partial_sumsq_kernel(const float4* __restrict__ p, const float4* __restrict__ t,
                     float* __restrict__ partials) {
    const int tid = blockIdx.x * THREADS + threadIdx.x;

    float4 a[ITERS], b[ITERS];
    #pragma unroll
    for (int k = 0; k < ITERS; ++k) a[k] = p[tid + k * STRIDE];
    #pragma unroll
    for (int k = 0; k < ITERS; ++k) b[k] = t[tid + k * STRIDE];

    float acc = 0.0f;
    #pragma unroll
    for (int k = 0; k < ITERS; ++k) {
        float dx = a[k].x - b[k].x;
        float dy = a[k].y - b[k].y;
        float dz = a[k].z - b[k].z;
        float dw = a[k].w - b[k].w;
        acc += dx * dx + dy * dy + dz * dz + dw * dw;
    }

    #pragma unroll
    for (int off = 32; off > 0; off >>= 1)
        acc += __shfl_down(acc, off, 64);

    __shared__ float smem[THREADS / 64];
    const int wid  = threadIdx.x >> 6;
    const int lane = threadIdx.x & 63;
    if (lane == 0) smem[wid] = acc;
    __syncthreads();
    if (threadIdx.x == 0)
        partials[blockIdx.x] = smem[0] + smem[1] + smem[2] + smem[3];
}

// ---------------------------------------------------------------------------
// Kernel 2: one block. Reduce 2048 partials; gather 32x2 traces (256 threads,
// 8 diag elements each); rank loss on wave 0; write the 3 outputs.
// ---------------------------------------------------------------------------
__global__ void __launch_bounds__(THREADS)
finish_kernel(const float* __restrict__ p, const float* __restrict__ t,
              const float* __restrict__ partials, float* __restrict__ out) {
    const int tid = threadIdx.x;

    // --- reduce 2048 partials: 8 per thread ---
    float s = 0.0f;
    #pragma unroll
    for (int k = 0; k < BLOCKS / THREADS; ++k)
        s += partials[tid + k * THREADS];

    // --- trace gather (independent loads, overlap with the above) ---
    const int mat  = tid >> 3;   // 0..31
    const int part = tid & 7;    // 0..7
    float tp = 0.0f, tr = 0.0f;
    #pragma unroll
    for (int i = 0; i < 8; ++i) {
        const int j = part * 8 + i;
        const size_t off = (size_t)mat * (DIM * DIM) + (size_t)j * (DIM + 1);
        tp += p[off];
        tr += t[off];
    }

    // block-reduce sumsq
    #pragma unroll
    for (int off = 32; off > 0; off >>= 1)
        s += __shfl_down(s, off, 64);
    __shared__ float smem[THREADS / 64];
    const int wid  = tid >> 6;
    const int lane = tid & 63;
    if (lane == 0) smem[wid] = s;

    // per-matrix traces via LDS
    __shared__ float redp[THREADS], redt[THREADS];
    redp[tid] = tp;
    redt[tid] = tr;
    __syncthreads();

    __shared__ float sp[MRANK], st[MRANK];
    if (tid < MRANK) {
        float s1 = 0.0f, s2 = 0.0f;
        #pragma unroll
        for (int i = 0; i < 8; ++i) {
            s1 += redp[tid * 8 + i];
            s2 += redt[tid * 8 + i];
        }
        sp[tid] = s1;
        st[tid] = s2;
    }
    __syncthreads();

    float racc = 0.0f;
    if (tid < MRANK) {
        const float pi = sp[tid];
        const float ti = st[tid];
        for (int j = tid + 1; j < MRANK; ++j) {
            float dt = ti - st[j];
            float dp = pi - sp[j];
            float c = 0.0f;
            if (dt > 0.0f)      c = fmaxf(-dp + GAMMA_C, 0.0f);
            else if (dt < 0.0f) c = fmaxf( dp + GAMMA_C, 0.0f);
            racc += c;
        }
    }
    if (tid < 64) {
        #pragma unroll
        for (int off = 32; off > 0; off >>= 1)
            racc += __shfl_down(racc, off, 64);
        if (tid == 0) {
            float total_ss = smem[0] + smem[1] + smem[2] + smem[3];
            float eff  = total_ss / (float)NTOT;
            float rank = racc / 496.0f;   // 32*31/2 pairs
            out[0] = eff + LAMBDA2_C * rank;
            out[1] = eff;
            out[2] = rank;
        }
    }
}

extern "C" void kernel_launch(void* const* d_in, const int* in_sizes, int n_in,
                              void* d_out, int out_size, void* d_ws, size_t ws_size,
                              hipStream_t stream) {
    const float* pred = (const float*)d_in[0];
    const float* tru  = (const float*)d_in[1];
    float* out = (float*)d_out;
    float* ws  = (float*)d_ws;   // 2048 floats of partials — fully overwritten
                                 // by kernel 1 every call, no init needed.

    partial_sumsq_kernel<<<BLOCKS, THREADS, 0, stream>>>(
        (const float4*)pred, (const float4*)tru, ws);

    finish_kernel<<<1, THREADS, 0, stream>>>(pred, tru, ws, out);
}